// Round 1
// baseline (418.972 us; speedup 1.0000x reference)
//
#include <hip/hip_runtime.h>
#include <math.h>

#define BB 4
#define NN 65536
#define G 64
#define G3 (G*G*G)
#define CF 32
#define HF 128
#define WF 128
#define VSc 0.05f
#define R2c 1.5625f   // 1.25^2, exactly representable

// d_ws layout (bytes):
//  [0, B*G3)                : occ bytes (memset 0)
//  ANY_OFF  = B*G3          : any[B] int (memset 0)
//  ACC_OFF  = ANY_OFF+16    : accum[B*4] float (memset 0)
//  W1T_OFF  = ACC_OFF+64    : W1T[64*35] float
//  FLG_OFF  = W1T_OFF+8960  : flags[B*N] int
#define ANY_OFF (BB*G3)
#define ACC_OFF (ANY_OFF + 16)
#define W1T_OFF (ACC_OFF + 64)
#define FLG_OFF (W1T_OFF + 8960)

__global__ __launch_bounds__(256) void transpose_w1(const float* __restrict__ W1,
                                                    float* __restrict__ W1T) {
    int i = blockIdx.x * 256 + threadIdx.x;
    if (i < 64 * 35) {
        int j = i / 35, k = i - j * 35;
        W1T[j * 35 + k] = W1[k * 64 + j];   // W1 is [35][64]
    }
}

__global__ __launch_bounds__(256) void points_kernel(const float* __restrict__ pts,
                                                     const float* __restrict__ pelvis,
                                                     int* __restrict__ flags,
                                                     int* __restrict__ any) {
    int idx = blockIdx.x * 256 + threadIdx.x;     // B*N threads
    int b = idx >> 16;                             // N = 65536
    const float* p = pts + (size_t)idx * 3;
    float px = p[0], py = p[1], pz = p[2];
    float ax = pelvis[b * 3 + 0], ay = pelvis[b * 3 + 1], az = pelvis[b * 3 + 2];

    float dx = px - ax, dy = py - ay, dz = pz - az;
    float rxy = dx * dx + dy * dy;
    float d0 = dz * dz;
    float dm = (dz + 0.5f) * (dz + 0.5f);   // anchor at az-0.5
    float dp = (dz - 0.5f) * (dz - 0.5f);   // anchor at az+0.5
    float mind2 = rxy + fminf(d0, fminf(dm, dp));
    bool nearby = mind2 <= R2c;

    int vx = (int)floorf(px / VSc);
    int vy = (int)floorf(py / VSc);
    int vz = (int)floorf(pz / VSc);
    int v0x = (int)floorf(ax / VSc) - 32;
    int v0y = (int)floorf(ay / VSc) - 32;
    int v0z = (int)floorf(az / VSc) - 32;
    int lx = vx - v0x, ly = vy - v0y, lz = vz - v0z;
    bool inb = ((unsigned)lx < 64u) && ((unsigned)ly < 64u) && ((unsigned)lz < 64u);
    int flat = (lx << 12) + (ly << 6) + lz;
    flags[idx] = inb ? (flat | (nearby ? (1 << 18) : 0)) : -1;

    unsigned long long bal = __ballot(nearby);
    if ((threadIdx.x & 63) == 0 && bal != 0ULL) atomicOr(&any[b], 1);
}

__global__ __launch_bounds__(256) void scatter_kernel(const int* __restrict__ flags,
                                                      const int* __restrict__ any,
                                                      unsigned char* __restrict__ occ) {
    int idx = blockIdx.x * 256 + threadIdx.x;
    int b = idx >> 16;
    int pk = flags[idx];
    if (pk >= 0) {
        bool nb = (pk >> 18) & 1;
        if (nb || any[b] == 0) occ[(size_t)b * G3 + (pk & 0x3FFFF)] = 1;
    }
}

__global__ __launch_bounds__(256) void voxel_kernel(
    const float* __restrict__ fmap, const float* __restrict__ pelvis,
    const float* __restrict__ Kmat, const float* __restrict__ bbx,
    const float* __restrict__ W1T, const float* __restrict__ b1,
    const float* __restrict__ W2, const float* __restrict__ b2,
    const unsigned char* __restrict__ occ, float* __restrict__ accum,
    float* __restrict__ outBig) {
    int blk = blockIdx.x;
    int b = blk >> 10;                       // G3/256 = 1024 blocks per batch
    int g = ((blk & 1023) << 8) + threadIdx.x;

    float ax = pelvis[b * 3 + 0], ay = pelvis[b * 3 + 1], az = pelvis[b * 3 + 2];
    float fx = Kmat[b * 9 + 0], fy = Kmat[b * 9 + 4];
    float cxp = Kmat[b * 9 + 2], cyp = Kmat[b * 9 + 5];
    float l = bbx[b * 4 + 0], t = bbx[b * 4 + 1];
    float r = bbx[b * 4 + 2], btm = bbx[b * 4 + 3];
    float inv_w = 1.0f / (r - l), inv_h = 1.0f / (btm - t);

    int v0x = (int)floorf(ax / VSc) - 32;
    int v0y = (int)floorf(ay / VSc) - 32;
    int v0z = (int)floorf(az / VSc) - 32;

    int gx = g >> 12, gy = (g >> 6) & 63, gz = g & 63;
    float cxx = (float)(v0x + gx) * VSc + 0.025f;
    float cyy = (float)(v0y + gy) * VSc + 0.025f;
    float czz = (float)(v0z + gz) * VSc + 0.025f;

    float feat[35];
    feat[0] = ax - cxx;
    feat[1] = ay - cyy;
    feat[2] = az - czz;

    // project
    float z = czz;
    float u = cxx / z * fx + cxp;
    float vp = cyy / z * fy + cyp;
    float uu = (u - l) * inv_w * (float)(WF - 1);
    float vv = (vp - t) * inv_h * (float)(HF - 1);
    float x0f = floorf(uu), y0f = floorf(vv);
    float wx = uu - x0f, wy = vv - y0f;
    int x0 = (int)x0f, y0 = (int)y0f;
    int x1 = x0 + 1, y1 = y0 + 1;
    bool mx0 = (unsigned)x0 < (unsigned)WF;
    bool mx1 = (unsigned)x1 < (unsigned)WF;
    bool my0 = (unsigned)y0 < (unsigned)HF;
    bool my1 = (unsigned)y1 < (unsigned)HF;
    int xc0 = min(max(x0, 0), WF - 1), xc1 = min(max(x1, 0), WF - 1);
    int yc0 = min(max(y0, 0), HF - 1), yc1 = min(max(y1, 0), HF - 1);
    float w00 = (1.0f - wx) * (1.0f - wy) * ((mx0 && my0) ? 1.0f : 0.0f);
    float w10 = wx * (1.0f - wy) * ((mx1 && my0) ? 1.0f : 0.0f);
    float w01 = (1.0f - wx) * wy * ((mx0 && my1) ? 1.0f : 0.0f);
    float w11 = wx * wy * ((mx1 && my1) ? 1.0f : 0.0f);
    int o00 = yc0 * WF + xc0, o10 = yc0 * WF + xc1;
    int o01 = yc1 * WF + xc0, o11 = yc1 * WF + xc1;

    const float* fb = fmap + (size_t)b * CF * HF * WF;
#pragma unroll
    for (int c = 0; c < CF; ++c) {
        const float* fc = fb + c * (HF * WF);
        float s = fc[o00] * w00;
        s = fmaf(fc[o10], w10, s);
        s = fmaf(fc[o01], w01, s);
        s = fmaf(fc[o11], w11, s);
        feat[3 + c] = s;
    }

    // MLP 35 -> 64 (relu) -> 12, weights via uniform (scalar) loads
    float o[12];
#pragma unroll
    for (int i = 0; i < 12; ++i) o[i] = b2[i];

#pragma unroll 4
    for (int j = 0; j < 64; ++j) {
        const float* w1r = W1T + j * 35;
        float acc = b1[j];
#pragma unroll
        for (int k = 0; k < 35; ++k) acc = fmaf(feat[k], w1r[k], acc);
        float hj = fmaxf(acc, 0.0f);
        const float* w2r = W2 + j * 12;
#pragma unroll
        for (int i = 0; i < 12; ++i) o[i] = fmaf(hj, w2r[i], o[i]);
    }

    // store out[12] (48B per thread, float4 x3)
    float4* dst = (float4*)(outBig + (size_t)(b * G3 + g) * 12);
    dst[0] = make_float4(o[0], o[1], o[2], o[3]);
    dst[1] = make_float4(o[4], o[5], o[6], o[7]);
    dst[2] = make_float4(o[8], o[9], o[10], o[11]);

    // softmax accumulation with fixed max M = 1 (s <= 1 always)
    float sig = 1.0f / (1.0f + expf(-o[0]));
    bool oc = occ[(size_t)b * G3 + g] != 0;
    float e = oc ? expf(sig - 1.0f) : 0.0f;
    float s0 = e;
    float s1 = e * (cxx + o[1]);
    float s2 = e * (cyy + o[2]);
    float s3 = e * (czz + o[3]);
#pragma unroll
    for (int off = 32; off > 0; off >>= 1) {
        s0 += __shfl_down(s0, off, 64);
        s1 += __shfl_down(s1, off, 64);
        s2 += __shfl_down(s2, off, 64);
        s3 += __shfl_down(s3, off, 64);
    }
    __shared__ float red[4][4];
    int wave = threadIdx.x >> 6, lane = threadIdx.x & 63;
    if (lane == 0) {
        red[wave][0] = s0; red[wave][1] = s1; red[wave][2] = s2; red[wave][3] = s3;
    }
    __syncthreads();
    if (threadIdx.x == 0) {
        float t0 = red[0][0] + red[1][0] + red[2][0] + red[3][0];
        float t1 = red[0][1] + red[1][1] + red[2][1] + red[3][1];
        float t2 = red[0][2] + red[1][2] + red[2][2] + red[3][2];
        float t3 = red[0][3] + red[1][3] + red[2][3] + red[3][3];
        atomicAdd(&accum[b * 4 + 0], t0);
        atomicAdd(&accum[b * 4 + 1], t1);
        atomicAdd(&accum[b * 4 + 2], t2);
        atomicAdd(&accum[b * 4 + 3], t3);
    }
}

__global__ void finalize_kernel(const float* __restrict__ accum,
                                const float* __restrict__ pelvis,
                                float* __restrict__ out) {
    int b = threadIdx.x;
    if (b < BB) {
        float den = accum[b * 4 + 0];
        float x = accum[b * 4 + 1] / den;
        float y = accum[b * 4 + 2] / den;
        float zz = accum[b * 4 + 3] / den;
        bool bad = isnan(x) || isnan(y) || isnan(zz);
        out[b * 3 + 0] = bad ? pelvis[b * 3 + 0] : x;
        out[b * 3 + 1] = bad ? pelvis[b * 3 + 1] : y;
        out[b * 3 + 2] = bad ? pelvis[b * 3 + 2] : zz;
    }
}

extern "C" void kernel_launch(void* const* d_in, const int* in_sizes, int n_in,
                              void* d_out, int out_size, void* d_ws, size_t ws_size,
                              hipStream_t stream) {
    const float* points = (const float*)d_in[0];
    const float* fmap   = (const float*)d_in[1];
    const float* pelvis = (const float*)d_in[2];
    const float* Kmat   = (const float*)d_in[3];
    const float* bbx    = (const float*)d_in[4];
    const float* W1     = (const float*)d_in[5];
    const float* b1     = (const float*)d_in[6];
    const float* W2     = (const float*)d_in[7];
    const float* b2     = (const float*)d_in[8];
    float* out = (float*)d_out;

    char* ws = (char*)d_ws;
    unsigned char* occ = (unsigned char*)ws;
    int* any     = (int*)(ws + ANY_OFF);
    float* accum = (float*)(ws + ACC_OFF);
    float* W1T   = (float*)(ws + W1T_OFF);
    int* flags   = (int*)(ws + FLG_OFF);

    // zero occ + any + accum
    hipMemsetAsync(ws, 0, ACC_OFF + 64, stream);

    transpose_w1<<<9, 256, 0, stream>>>(W1, W1T);
    points_kernel<<<(BB * NN) / 256, 256, 0, stream>>>(points, pelvis, flags, any);
    scatter_kernel<<<(BB * NN) / 256, 256, 0, stream>>>(flags, any, occ);
    voxel_kernel<<<(BB * G3) / 256, 256, 0, stream>>>(fmap, pelvis, Kmat, bbx,
                                                      W1T, b1, W2, b2, occ, accum,
                                                      out + 12);
    finalize_kernel<<<1, 64, 0, stream>>>(accum, pelvis, out);
}

// Round 2
// 352.655 us; speedup vs baseline: 1.1881x; 1.1881x over previous
//
#include <hip/hip_runtime.h>
#include <math.h>

#define BB 4
#define NN 65536
#define G 64
#define G3 (G*G*G)
#define CF 32
#define HF 128
#define WF 128
#define VSc 0.05f
#define R2c 1.5625f   // 1.25^2, exactly representable

// d_ws layout (bytes):
//  [0, B*G3)                : occ bytes (memset 0)           1 MB
//  ANY_OFF  = B*G3          : any[B] int (memset 0)
//  ACC_OFF  = ANY_OFF+16    : accum[B*4] float (memset 0)
//  W1T_OFF  = ACC_OFF+64    : W1T[64*35] float
//  FLG_OFF  = W1T_OFF+8960  : flags[B*N] int                 1 MB
//  FMT_OFF  = FLG_OFF+1MB   : fmapT[B][H][W][C] float        8.4 MB
#define ANY_OFF (BB*G3)
#define ACC_OFF (ANY_OFF + 16)
#define W1T_OFF (ACC_OFF + 64)
#define FLG_OFF (W1T_OFF + 8960)
#define FMT_OFF (FLG_OFF + BB*NN*4)

__global__ __launch_bounds__(256) void transpose_w1(const float* __restrict__ W1,
                                                    float* __restrict__ W1T) {
    int i = blockIdx.x * 256 + threadIdx.x;
    if (i < 64 * 35) {
        int j = i / 35, k = i - j * 35;
        W1T[j * 35 + k] = W1[k * 64 + j];   // W1 is [35][64]
    }
}

// [B,C,H,W] -> [B,H,W,C], LDS-tiled. Block: one (b, y, 64-px x-chunk).
__global__ __launch_bounds__(256) void transpose_fmap(const float* __restrict__ fmap,
                                                      float* __restrict__ fmapT) {
    __shared__ float tile[CF][65];
    int bi = blockIdx.x;                // B*HF*(WF/64) = 1024
    int xc = (bi & 1) * 64;
    int y  = (bi >> 1) & (HF - 1);
    int b  = bi >> 8;
    int t = threadIdx.x;
#pragma unroll
    for (int i = 0; i < 8; ++i) {
        int e = i * 256 + t;
        int c = e >> 6, p = e & 63;     // coalesced over p
        tile[c][p] = fmap[(((size_t)b * CF + c) * HF + y) * WF + xc + p];
    }
    __syncthreads();
#pragma unroll
    for (int i = 0; i < 8; ++i) {
        int e = i * 256 + t;
        int p = e >> 5, c = e & 31;     // coalesced over (p,c)
        fmapT[(((size_t)b * HF + y) * WF + xc + p) * CF + c] = tile[c][p];
    }
}

__global__ __launch_bounds__(256) void points_kernel(const float* __restrict__ pts,
                                                     const float* __restrict__ pelvis,
                                                     int* __restrict__ flags,
                                                     int* __restrict__ any) {
    int idx = blockIdx.x * 256 + threadIdx.x;     // B*N threads
    int b = idx >> 16;                             // N = 65536
    const float* p = pts + (size_t)idx * 3;
    float px = p[0], py = p[1], pz = p[2];
    float ax = pelvis[b * 3 + 0], ay = pelvis[b * 3 + 1], az = pelvis[b * 3 + 2];

    float dx = px - ax, dy = py - ay, dz = pz - az;
    float rxy = dx * dx + dy * dy;
    float d0 = dz * dz;
    float dm = (dz + 0.5f) * (dz + 0.5f);   // anchor at az-0.5
    float dp = (dz - 0.5f) * (dz - 0.5f);   // anchor at az+0.5
    float mind2 = rxy + fminf(d0, fminf(dm, dp));
    bool nearby = mind2 <= R2c;

    int vx = (int)floorf(px / VSc);
    int vy = (int)floorf(py / VSc);
    int vz = (int)floorf(pz / VSc);
    int v0x = (int)floorf(ax / VSc) - 32;
    int v0y = (int)floorf(ay / VSc) - 32;
    int v0z = (int)floorf(az / VSc) - 32;
    int lx = vx - v0x, ly = vy - v0y, lz = vz - v0z;
    bool inb = ((unsigned)lx < 64u) && ((unsigned)ly < 64u) && ((unsigned)lz < 64u);
    int flat = (lx << 12) + (ly << 6) + lz;
    flags[idx] = inb ? (flat | (nearby ? (1 << 18) : 0)) : -1;

    unsigned long long bal = __ballot(nearby);
    if ((threadIdx.x & 63) == 0 && bal != 0ULL) atomicOr(&any[b], 1);
}

__global__ __launch_bounds__(256) void scatter_kernel(const int* __restrict__ flags,
                                                      const int* __restrict__ any,
                                                      unsigned char* __restrict__ occ) {
    int idx = blockIdx.x * 256 + threadIdx.x;
    int b = idx >> 16;
    int pk = flags[idx];
    if (pk >= 0) {
        bool nb = (pk >> 18) & 1;
        if (nb || any[b] == 0) occ[(size_t)b * G3 + (pk & 0x3FFFF)] = 1;
    }
}

__global__ __launch_bounds__(256, 4) void voxel_kernel(
    const float* __restrict__ fmapT, const float* __restrict__ pelvis,
    const float* __restrict__ Kmat, const float* __restrict__ bbx,
    const float* __restrict__ W1T, const float* __restrict__ b1,
    const float* __restrict__ W2, const float* __restrict__ b2,
    const unsigned char* __restrict__ occ, float* __restrict__ accum,
    float* __restrict__ outBig) {
    int blk = blockIdx.x;
    int b = blk >> 10;                       // G3/256 = 1024 blocks per batch
    int g = ((blk & 1023) << 8) + threadIdx.x;

    float ax = pelvis[b * 3 + 0], ay = pelvis[b * 3 + 1], az = pelvis[b * 3 + 2];
    float fx = Kmat[b * 9 + 0], fy = Kmat[b * 9 + 4];
    float cxp = Kmat[b * 9 + 2], cyp = Kmat[b * 9 + 5];
    float l = bbx[b * 4 + 0], t = bbx[b * 4 + 1];
    float r = bbx[b * 4 + 2], btm = bbx[b * 4 + 3];
    float inv_w = 1.0f / (r - l), inv_h = 1.0f / (btm - t);

    int v0x = (int)floorf(ax / VSc) - 32;
    int v0y = (int)floorf(ay / VSc) - 32;
    int v0z = (int)floorf(az / VSc) - 32;

    int gx = g >> 12, gy = (g >> 6) & 63, gz = g & 63;
    float cxx = (float)(v0x + gx) * VSc + 0.025f;
    float cyy = (float)(v0y + gy) * VSc + 0.025f;
    float czz = (float)(v0z + gz) * VSc + 0.025f;

    float feat[35];
    feat[0] = ax - cxx;
    feat[1] = ay - cyy;
    feat[2] = az - czz;

    // project
    float z = czz;
    float u = cxx / z * fx + cxp;
    float vp = cyy / z * fy + cyp;
    float uu = (u - l) * inv_w * (float)(WF - 1);
    float vv = (vp - t) * inv_h * (float)(HF - 1);
    float x0f = floorf(uu), y0f = floorf(vv);
    float wx = uu - x0f, wy = vv - y0f;
    int x0 = (int)x0f, y0 = (int)y0f;
    int x1 = x0 + 1, y1 = y0 + 1;
    bool mx0 = (unsigned)x0 < (unsigned)WF;
    bool mx1 = (unsigned)x1 < (unsigned)WF;
    bool my0 = (unsigned)y0 < (unsigned)HF;
    bool my1 = (unsigned)y1 < (unsigned)HF;
    int xc0 = min(max(x0, 0), WF - 1), xc1 = min(max(x1, 0), WF - 1);
    int yc0 = min(max(y0, 0), HF - 1), yc1 = min(max(y1, 0), HF - 1);
    float w00 = (1.0f - wx) * (1.0f - wy) * ((mx0 && my0) ? 1.0f : 0.0f);
    float w10 = wx * (1.0f - wy) * ((mx1 && my0) ? 1.0f : 0.0f);
    float w01 = (1.0f - wx) * wy * ((mx0 && my1) ? 1.0f : 0.0f);
    float w11 = wx * wy * ((mx1 && my1) ? 1.0f : 0.0f);

    // [H,W,C] layout: each corner is 32 contiguous floats
    const float* fb = fmapT + (size_t)b * HF * WF * CF;
    const float* p00 = fb + (yc0 * WF + xc0) * CF;
    const float* p10 = fb + (yc0 * WF + xc1) * CF;
    const float* p01 = fb + (yc1 * WF + xc0) * CF;
    const float* p11 = fb + (yc1 * WF + xc1) * CF;
#pragma unroll
    for (int c = 0; c < CF; c += 4) {
        float4 a00 = *(const float4*)(p00 + c);
        float4 a10 = *(const float4*)(p10 + c);
        float4 a01 = *(const float4*)(p01 + c);
        float4 a11 = *(const float4*)(p11 + c);
        feat[3 + c + 0] = fmaf(a11.x, w11, fmaf(a01.x, w01, fmaf(a10.x, w10, a00.x * w00)));
        feat[3 + c + 1] = fmaf(a11.y, w11, fmaf(a01.y, w01, fmaf(a10.y, w10, a00.y * w00)));
        feat[3 + c + 2] = fmaf(a11.z, w11, fmaf(a01.z, w01, fmaf(a10.z, w10, a00.z * w00)));
        feat[3 + c + 3] = fmaf(a11.w, w11, fmaf(a01.w, w01, fmaf(a10.w, w10, a00.w * w00)));
    }

    // MLP 35 -> 64 (relu) -> 12, weights via uniform (scalar) loads
    float o[12];
#pragma unroll
    for (int i = 0; i < 12; ++i) o[i] = b2[i];

#pragma unroll 4
    for (int j = 0; j < 64; ++j) {
        const float* w1r = W1T + j * 35;
        float acc = b1[j];
#pragma unroll
        for (int k = 0; k < 35; ++k) acc = fmaf(feat[k], w1r[k], acc);
        float hj = fmaxf(acc, 0.0f);
        const float* w2r = W2 + j * 12;
#pragma unroll
        for (int i = 0; i < 12; ++i) o[i] = fmaf(hj, w2r[i], o[i]);
    }

    // store out[12] (48B per thread, float4 x3)
    float4* dst = (float4*)(outBig + (size_t)(b * G3 + g) * 12);
    dst[0] = make_float4(o[0], o[1], o[2], o[3]);
    dst[1] = make_float4(o[4], o[5], o[6], o[7]);
    dst[2] = make_float4(o[8], o[9], o[10], o[11]);

    // softmax accumulation with fixed max M = 1 (s <= 1 always)
    float sig = 1.0f / (1.0f + expf(-o[0]));
    bool oc = occ[(size_t)b * G3 + g] != 0;
    float e = oc ? expf(sig - 1.0f) : 0.0f;
    float s0 = e;
    float s1 = e * (cxx + o[1]);
    float s2 = e * (cyy + o[2]);
    float s3 = e * (czz + o[3]);
#pragma unroll
    for (int off = 32; off > 0; off >>= 1) {
        s0 += __shfl_down(s0, off, 64);
        s1 += __shfl_down(s1, off, 64);
        s2 += __shfl_down(s2, off, 64);
        s3 += __shfl_down(s3, off, 64);
    }
    __shared__ float red[4][4];
    int wave = threadIdx.x >> 6, lane = threadIdx.x & 63;
    if (lane == 0) {
        red[wave][0] = s0; red[wave][1] = s1; red[wave][2] = s2; red[wave][3] = s3;
    }
    __syncthreads();
    if (threadIdx.x == 0) {
        float t0 = red[0][0] + red[1][0] + red[2][0] + red[3][0];
        float t1 = red[0][1] + red[1][1] + red[2][1] + red[3][1];
        float t2 = red[0][2] + red[1][2] + red[2][2] + red[3][2];
        float t3 = red[0][3] + red[1][3] + red[2][3] + red[3][3];
        atomicAdd(&accum[b * 4 + 0], t0);
        atomicAdd(&accum[b * 4 + 1], t1);
        atomicAdd(&accum[b * 4 + 2], t2);
        atomicAdd(&accum[b * 4 + 3], t3);
    }
}

__global__ void finalize_kernel(const float* __restrict__ accum,
                                const float* __restrict__ pelvis,
                                float* __restrict__ out) {
    int b = threadIdx.x;
    if (b < BB) {
        float den = accum[b * 4 + 0];
        float x = accum[b * 4 + 1] / den;
        float y = accum[b * 4 + 2] / den;
        float zz = accum[b * 4 + 3] / den;
        bool bad = isnan(x) || isnan(y) || isnan(zz);
        out[b * 3 + 0] = bad ? pelvis[b * 3 + 0] : x;
        out[b * 3 + 1] = bad ? pelvis[b * 3 + 1] : y;
        out[b * 3 + 2] = bad ? pelvis[b * 3 + 2] : zz;
    }
}

extern "C" void kernel_launch(void* const* d_in, const int* in_sizes, int n_in,
                              void* d_out, int out_size, void* d_ws, size_t ws_size,
                              hipStream_t stream) {
    const float* points = (const float*)d_in[0];
    const float* fmap   = (const float*)d_in[1];
    const float* pelvis = (const float*)d_in[2];
    const float* Kmat   = (const float*)d_in[3];
    const float* bbx    = (const float*)d_in[4];
    const float* W1     = (const float*)d_in[5];
    const float* b1     = (const float*)d_in[6];
    const float* W2     = (const float*)d_in[7];
    const float* b2     = (const float*)d_in[8];
    float* out = (float*)d_out;

    char* ws = (char*)d_ws;
    unsigned char* occ = (unsigned char*)ws;
    int* any     = (int*)(ws + ANY_OFF);
    float* accum = (float*)(ws + ACC_OFF);
    float* W1T   = (float*)(ws + W1T_OFF);
    int* flags   = (int*)(ws + FLG_OFF);
    float* fmapT = (float*)(ws + FMT_OFF);

    // zero occ + any + accum
    hipMemsetAsync(ws, 0, ACC_OFF + 64, stream);

    transpose_w1<<<9, 256, 0, stream>>>(W1, W1T);
    transpose_fmap<<<BB * HF * (WF / 64), 256, 0, stream>>>(fmap, fmapT);
    points_kernel<<<(BB * NN) / 256, 256, 0, stream>>>(points, pelvis, flags, any);
    scatter_kernel<<<(BB * NN) / 256, 256, 0, stream>>>(flags, any, occ);
    voxel_kernel<<<(BB * G3) / 256, 256, 0, stream>>>(fmapT, pelvis, Kmat, bbx,
                                                      W1T, b1, W2, b2, occ, accum,
                                                      out + 12);
    finalize_kernel<<<1, 64, 0, stream>>>(accum, pelvis, out);
}

// Round 3
// 231.828 us; speedup vs baseline: 1.8073x; 1.5212x over previous
//
#include <hip/hip_runtime.h>
#include <math.h>

#define BB 4
#define NN 65536
#define G 64
#define G3 (G*G*G)
#define CF 32
#define HF 128
#define WF 128
#define VSc 0.05f
#define R2c 1.5625f   // 1.25^2, exactly representable

// d_ws layout (bytes):
//  [0, B*G3)            : occ bytes, 2-bit flags (bit0 = inb&nearby, bit1 = inb)  1 MB (memset 0)
//  ANY_OFF = B*G3       : any[B] int (memset 0)
//  PART_OFF = +64       : partials[4096] float4 (fully written each launch)      64 KB
//  FMT_OFF              : fmapT[B][H][W][C] float                                 8.4 MB
#define ANY_OFF  (BB*G3)
#define PART_OFF (ANY_OFF + 64)
#define FMT_OFF  (PART_OFF + 4096*16)

typedef __attribute__((ext_vector_type(8))) short short8;
typedef __attribute__((ext_vector_type(4))) float floatx4;

__device__ __forceinline__ ushort f2bf(float x) {
    union { float f; unsigned u; } v; v.f = x;
    unsigned r = v.u + 0x7FFF + ((v.u >> 16) & 1);   // RNE
    return (ushort)(r >> 16);
}

// ---------- points: flags + any, fused scatter via atomicOr ----------
__global__ __launch_bounds__(256) void points_kernel(const float* __restrict__ pts,
                                                     const float* __restrict__ pelvis,
                                                     unsigned* __restrict__ occW,
                                                     int* __restrict__ any) {
    int idx = blockIdx.x * 256 + threadIdx.x;     // B*N threads
    int b = idx >> 16;                             // N = 65536
    const float* p = pts + (size_t)idx * 3;
    float px = p[0], py = p[1], pz = p[2];
    float ax = pelvis[b * 3 + 0], ay = pelvis[b * 3 + 1], az = pelvis[b * 3 + 2];

    float dx = px - ax, dy = py - ay, dz = pz - az;
    float rxy = dx * dx + dy * dy;
    float d0 = dz * dz;
    float dm = (dz + 0.5f) * (dz + 0.5f);
    float dp = (dz - 0.5f) * (dz - 0.5f);
    float mind2 = rxy + fminf(d0, fminf(dm, dp));
    bool nearby = mind2 <= R2c;

    int vx = (int)floorf(px / VSc);
    int vy = (int)floorf(py / VSc);
    int vz = (int)floorf(pz / VSc);
    int v0x = (int)floorf(ax / VSc) - 32;
    int v0y = (int)floorf(ay / VSc) - 32;
    int v0z = (int)floorf(az / VSc) - 32;
    int lx = vx - v0x, ly = vy - v0y, lz = vz - v0z;
    bool inb = ((unsigned)lx < 64u) && ((unsigned)ly < 64u) && ((unsigned)lz < 64u);
    if (inb) {
        int flat = b * G3 + (lx << 12) + (ly << 6) + lz;
        unsigned mask = (nearby ? 3u : 2u) << ((flat & 3) * 8);
        atomicOr(&occW[flat >> 2], mask);
    }
    unsigned long long bal = __ballot(nearby);
    if ((threadIdx.x & 63) == 0 && bal != 0ULL) atomicOr(&any[b], 1);
}

// ---------- [B,C,H,W] -> [B,H,W,C] ----------
__global__ __launch_bounds__(256) void transpose_fmap(const float* __restrict__ fmap,
                                                      float* __restrict__ fmapT) {
    __shared__ float tile[CF][65];
    int bi = blockIdx.x;                // B*HF*(WF/64) = 1024
    int xc = (bi & 1) * 64;
    int y  = (bi >> 1) & (HF - 1);
    int b  = bi >> 8;
    int t = threadIdx.x;
#pragma unroll
    for (int i = 0; i < 8; ++i) {
        int e = i * 256 + t;
        int c = e >> 6, p = e & 63;
        tile[c][p] = fmap[(((size_t)b * CF + c) * HF + y) * WF + xc + p];
    }
    __syncthreads();
#pragma unroll
    for (int i = 0; i < 8; ++i) {
        int e = i * 256 + t;
        int p = e >> 5, c = e & 31;
        fmapT[(((size_t)b * HF + y) * WF + xc + p) * CF + c] = tile[c][p];
    }
}

// ---------- voxel: bilinear gather + MFMA MLP ----------
// Per wave: 64 voxels. A-tile [64 x 64] bf16 in LDS (row stride 72 ushorts = 144 B).
// Layer1: C1[64x64] = A(feat) * W1p ; Layer2: C2[64x16] = A(h) * W2p.
__global__ __launch_bounds__(256, 2) void voxel_kernel(
    const float* __restrict__ fmapT, const float* __restrict__ pelvis,
    const float* __restrict__ Kmat, const float* __restrict__ bbx,
    const float* __restrict__ W1, const float* __restrict__ b1,
    const float* __restrict__ W2, const float* __restrict__ b2,
    const unsigned char* __restrict__ occ, const int* __restrict__ any,
    float4* __restrict__ partials, float* __restrict__ outBig) {
    __shared__ __align__(16) char ldsRaw[4][9216];
    __shared__ float red[4][4];

    int blk = blockIdx.x;
    int b = blk >> 10;
    int wv = threadIdx.x >> 6, lane = threadIdx.x & 63;
    int quad = lane >> 4, n16 = lane & 15;
    int g = ((blk & 1023) << 8) + (wv << 6) + lane;
    ushort* A = (ushort*)ldsRaw[wv];

    float ax = pelvis[b * 3 + 0], ay = pelvis[b * 3 + 1], az = pelvis[b * 3 + 2];
    float fx = Kmat[b * 9 + 0], fy = Kmat[b * 9 + 4];
    float cxp = Kmat[b * 9 + 2], cyp = Kmat[b * 9 + 5];
    float l = bbx[b * 4 + 0], t = bbx[b * 4 + 1];
    float r = bbx[b * 4 + 2], btm = bbx[b * 4 + 3];
    float inv_w = 1.0f / (r - l), inv_h = 1.0f / (btm - t);

    int v0x = (int)floorf(ax / VSc) - 32;
    int v0y = (int)floorf(ay / VSc) - 32;
    int v0z = (int)floorf(az / VSc) - 32;

    int gx = g >> 12, gy = (g >> 6) & 63, gz = g & 63;
    float cxx = (float)(v0x + gx) * VSc + 0.025f;
    float cyy = (float)(v0y + gy) * VSc + 0.025f;
    float czz = (float)(v0z + gz) * VSc + 0.025f;

    // ---- feat: [0..31] = bilinear fmap, [32..34] = geo ----
    float feat[35];
    feat[32] = ax - cxx;
    feat[33] = ay - cyy;
    feat[34] = az - czz;

    float z = czz;
    float u = cxx / z * fx + cxp;
    float vp = cyy / z * fy + cyp;
    float uu = (u - l) * inv_w * (float)(WF - 1);
    float vv = (vp - t) * inv_h * (float)(HF - 1);
    float x0f = floorf(uu), y0f = floorf(vv);
    float wx = uu - x0f, wy = vv - y0f;
    int x0 = (int)x0f, y0 = (int)y0f;
    int x1 = x0 + 1, y1 = y0 + 1;
    bool mx0 = (unsigned)x0 < (unsigned)WF;
    bool mx1 = (unsigned)x1 < (unsigned)WF;
    bool my0 = (unsigned)y0 < (unsigned)HF;
    bool my1 = (unsigned)y1 < (unsigned)HF;
    int xc0 = min(max(x0, 0), WF - 1), xc1 = min(max(x1, 0), WF - 1);
    int yc0 = min(max(y0, 0), HF - 1), yc1 = min(max(y1, 0), HF - 1);
    float w00 = (1.0f - wx) * (1.0f - wy) * ((mx0 && my0) ? 1.0f : 0.0f);
    float w10 = wx * (1.0f - wy) * ((mx1 && my0) ? 1.0f : 0.0f);
    float w01 = (1.0f - wx) * wy * ((mx0 && my1) ? 1.0f : 0.0f);
    float w11 = wx * wy * ((mx1 && my1) ? 1.0f : 0.0f);

    const float* fb = fmapT + (size_t)b * HF * WF * CF;
    const float* p00 = fb + (yc0 * WF + xc0) * CF;
    const float* p10 = fb + (yc0 * WF + xc1) * CF;
    const float* p01 = fb + (yc1 * WF + xc0) * CF;
    const float* p11 = fb + (yc1 * WF + xc1) * CF;
#pragma unroll
    for (int c = 0; c < CF; c += 4) {
        float4 a00 = *(const float4*)(p00 + c);
        float4 a10 = *(const float4*)(p10 + c);
        float4 a01 = *(const float4*)(p01 + c);
        float4 a11 = *(const float4*)(p11 + c);
        feat[c + 0] = fmaf(a11.x, w11, fmaf(a01.x, w01, fmaf(a10.x, w10, a00.x * w00)));
        feat[c + 1] = fmaf(a11.y, w11, fmaf(a01.y, w01, fmaf(a10.y, w10, a00.y * w00)));
        feat[c + 2] = fmaf(a11.z, w11, fmaf(a01.z, w01, fmaf(a10.z, w10, a00.z * w00)));
        feat[c + 3] = fmaf(a11.w, w11, fmaf(a01.w, w01, fmaf(a10.w, w10, a00.w * w00)));
    }

    // ---- pack feat -> bf16 LDS A-tile, K padded to 64 ----
#pragma unroll
    for (int i = 0; i < 8; ++i) {
        short8 pk;
#pragma unroll
        for (int e = 0; e < 8; ++e) {
            int k = i * 8 + e;
            pk[e] = (short)((k < 35) ? f2bf(feat[k]) : 0);
        }
        *(short8*)(A + lane * 72 + i * 8) = pk;
    }

    // ---- weight B-fragments (per-lane; identical across waves -> L1 broadcast) ----
    // B layout: lane holds B[k = quad*8+j][n = lane&15]
    short8 B1f[2][4];
#pragma unroll
    for (int kt = 0; kt < 2; ++kt)
#pragma unroll
        for (int nt = 0; nt < 4; ++nt) {
            short8 w;
#pragma unroll
            for (int j = 0; j < 8; ++j) {
                int kk = kt * 32 + quad * 8 + j;
                // feat k 0..31 -> W1 row 3+k ; feat k 32..34 -> W1 row k-32 ; else 0
                int row = (kk < 32) ? (3 + kk) : (kk - 32);
                w[j] = (kk < 35) ? (short)f2bf(W1[row * 64 + nt * 16 + n16]) : (short)0;
            }
            B1f[kt][nt] = w;
        }
    short8 B2f[2];
#pragma unroll
    for (int kt = 0; kt < 2; ++kt) {
        short8 w;
#pragma unroll
        for (int j = 0; j < 8; ++j) {
            int kk = kt * 32 + quad * 8 + j;
            w[j] = (n16 < 12) ? (short)f2bf(W2[kk * 12 + n16]) : (short)0;
        }
        B2f[kt] = w;
    }
    float b1v[4];
#pragma unroll
    for (int nt = 0; nt < 4; ++nt) b1v[nt] = b1[nt * 16 + n16];
    float b2v = (n16 < 12) ? b2[n16] : 0.0f;

    // ---- layer 1: 32 MFMA ----
    floatx4 c1[4][4];
#pragma unroll
    for (int mt = 0; mt < 4; ++mt)
#pragma unroll
        for (int nt = 0; nt < 4; ++nt) {
            floatx4 c = {b1v[nt], b1v[nt], b1v[nt], b1v[nt]};
            c1[mt][nt] = c;
        }
#pragma unroll
    for (int mt = 0; mt < 4; ++mt) {
        short8 a0 = *(short8*)(A + (mt * 16 + n16) * 72 + quad * 8);
        short8 a1 = *(short8*)(A + (mt * 16 + n16) * 72 + 32 + quad * 8);
#pragma unroll
        for (int nt = 0; nt < 4; ++nt) {
            c1[mt][nt] = __builtin_amdgcn_mfma_f32_16x16x32_bf16(a0, B1f[0][nt], c1[mt][nt], 0, 0, 0);
            c1[mt][nt] = __builtin_amdgcn_mfma_f32_16x16x32_bf16(a1, B1f[1][nt], c1[mt][nt], 0, 0, 0);
        }
    }

    // ---- relu -> bf16 -> LDS (h becomes the next A-tile) ----
    // C layout: lane holds (row = quad*4+r, col = n16) per tile
#pragma unroll
    for (int mt = 0; mt < 4; ++mt)
#pragma unroll
        for (int nt = 0; nt < 4; ++nt)
#pragma unroll
            for (int rr = 0; rr < 4; ++rr) {
                float hv = fmaxf(c1[mt][nt][rr], 0.0f);
                A[(mt * 16 + quad * 4 + rr) * 72 + nt * 16 + n16] = f2bf(hv);
            }

    // ---- layer 2: 8 MFMA ----
    floatx4 c2[4];
#pragma unroll
    for (int mt = 0; mt < 4; ++mt) {
        floatx4 c = {b2v, b2v, b2v, b2v};
        c2[mt] = c;
    }
#pragma unroll
    for (int mt = 0; mt < 4; ++mt) {
        short8 a0 = *(short8*)(A + (mt * 16 + n16) * 72 + quad * 8);
        short8 a1 = *(short8*)(A + (mt * 16 + n16) * 72 + 32 + quad * 8);
        c2[mt] = __builtin_amdgcn_mfma_f32_16x16x32_bf16(a0, B2f[0], c2[mt], 0, 0, 0);
        c2[mt] = __builtin_amdgcn_mfma_f32_16x16x32_bf16(a1, B2f[1], c2[mt], 0, 0, 0);
    }

    // ---- C2 -> LDS (stride 20 floats) -> per-lane out[12] ----
    float* O = (float*)ldsRaw[wv];
#pragma unroll
    for (int mt = 0; mt < 4; ++mt)
#pragma unroll
        for (int rr = 0; rr < 4; ++rr)
            O[(mt * 16 + quad * 4 + rr) * 20 + n16] = c2[mt][rr];

    float4 o0 = *(float4*)(O + lane * 20 + 0);
    float4 o1 = *(float4*)(O + lane * 20 + 4);
    float4 o2 = *(float4*)(O + lane * 20 + 8);

    float4* dst = (float4*)(outBig + (size_t)(b * G3 + g) * 12);
    dst[0] = o0; dst[1] = o1; dst[2] = o2;

    // ---- softmax accumulation, fixed max M = 1 ----
    float sig = 1.0f / (1.0f + expf(-o0.x));
    unsigned char oc = occ[(size_t)b * G3 + g];
    bool on = (oc & 1) || ((oc & 2) && any[b] == 0);
    float e = on ? expf(sig - 1.0f) : 0.0f;
    float s0 = e;
    float s1 = e * (cxx + o0.y);
    float s2 = e * (cyy + o0.z);
    float s3 = e * (czz + o0.w);
#pragma unroll
    for (int off = 32; off > 0; off >>= 1) {
        s0 += __shfl_down(s0, off, 64);
        s1 += __shfl_down(s1, off, 64);
        s2 += __shfl_down(s2, off, 64);
        s3 += __shfl_down(s3, off, 64);
    }
    if ((threadIdx.x & 63) == 0) {
        red[wv][0] = s0; red[wv][1] = s1; red[wv][2] = s2; red[wv][3] = s3;
    }
    __syncthreads();
    if (threadIdx.x == 0) {
        float t0 = red[0][0] + red[1][0] + red[2][0] + red[3][0];
        float t1 = red[0][1] + red[1][1] + red[2][1] + red[3][1];
        float t2 = red[0][2] + red[1][2] + red[2][2] + red[3][2];
        float t3 = red[0][3] + red[1][3] + red[2][3] + red[3][3];
        partials[blk] = make_float4(t0, t1, t2, t3);
    }
}

// ---------- reduce 1024 partials per batch + refined ----------
__global__ __launch_bounds__(256) void reduce_kernel(const float4* __restrict__ partials,
                                                     const float* __restrict__ pelvis,
                                                     float* __restrict__ out) {
    __shared__ float sh[4][256];
    int b = blockIdx.x, t = threadIdx.x;
    float s0 = 0, s1 = 0, s2 = 0, s3 = 0;
#pragma unroll
    for (int i = 0; i < 4; ++i) {
        float4 p = partials[b * 1024 + i * 256 + t];
        s0 += p.x; s1 += p.y; s2 += p.z; s3 += p.w;
    }
    sh[0][t] = s0; sh[1][t] = s1; sh[2][t] = s2; sh[3][t] = s3;
    __syncthreads();
    for (int st = 128; st > 0; st >>= 1) {
        if (t < st) {
            sh[0][t] += sh[0][t + st];
            sh[1][t] += sh[1][t + st];
            sh[2][t] += sh[2][t + st];
            sh[3][t] += sh[3][t + st];
        }
        __syncthreads();
    }
    if (t == 0) {
        float den = sh[0][0];
        float x = sh[1][0] / den;
        float y = sh[2][0] / den;
        float zz = sh[3][0] / den;
        bool bad = isnan(x) || isnan(y) || isnan(zz);
        out[b * 3 + 0] = bad ? pelvis[b * 3 + 0] : x;
        out[b * 3 + 1] = bad ? pelvis[b * 3 + 1] : y;
        out[b * 3 + 2] = bad ? pelvis[b * 3 + 2] : zz;
    }
}

extern "C" void kernel_launch(void* const* d_in, const int* in_sizes, int n_in,
                              void* d_out, int out_size, void* d_ws, size_t ws_size,
                              hipStream_t stream) {
    const float* points = (const float*)d_in[0];
    const float* fmap   = (const float*)d_in[1];
    const float* pelvis = (const float*)d_in[2];
    const float* Kmat   = (const float*)d_in[3];
    const float* bbx    = (const float*)d_in[4];
    const float* W1     = (const float*)d_in[5];
    const float* b1     = (const float*)d_in[6];
    const float* W2     = (const float*)d_in[7];
    const float* b2     = (const float*)d_in[8];
    float* out = (float*)d_out;

    char* ws = (char*)d_ws;
    unsigned char* occ = (unsigned char*)ws;
    int* any        = (int*)(ws + ANY_OFF);
    float4* partials= (float4*)(ws + PART_OFF);
    float* fmapT    = (float*)(ws + FMT_OFF);

    hipMemsetAsync(ws, 0, ANY_OFF + 64, stream);

    points_kernel<<<(BB * NN) / 256, 256, 0, stream>>>(points, pelvis, (unsigned*)occ, any);
    transpose_fmap<<<BB * HF * (WF / 64), 256, 0, stream>>>(fmap, fmapT);
    voxel_kernel<<<(BB * G3) / 256, 256, 0, stream>>>(fmapT, pelvis, Kmat, bbx,
                                                      W1, b1, W2, b2, occ, any,
                                                      partials, out + 12);
    reduce_kernel<<<BB, 256, 0, stream>>>(partials, pelvis, out);
}